// Round 6
// baseline (825.839 us; speedup 1.0000x reference)
//
#include <hip/hip_runtime.h>
#include <math.h>

#define O_CH 32
#define I_CH 3
#define IH 512
#define IW 512
#define OH 510
#define OW 510
#define N_IMG 16
#define WSTRIDE 32       // weight row stride in d_ws

typedef float v2f __attribute__((ext_vector_type(2)));

__global__ __launch_bounds__(256) void gabor_weights_kernel(
    const float* __restrict__ freq, const float* __restrict__ theta,
    const float* __restrict__ psi, const float* __restrict__ sigma,
    float* __restrict__ wp) {
  int idx = blockIdx.x * 256 + threadIdx.x;
  if (idx >= O_CH * I_CH * 9) return;
  int o = idx / 27;
  int rem = idx % 27;          // rem = c*9 + kh*3 + kw
  int kh = (rem / 3) % 3;
  int kw = rem % 3;
  // linspace(-ceil(3/2)+1, ceil(3/2), 3) = {-1, 0.5, 2}
  float x = (kw == 0) ? -1.0f : (kw == 1 ? 0.5f : 2.0f);
  float y = (kh == 0) ? -1.0f : (kh == 1 ? 0.5f : 2.0f);
  int pi = o * I_CH + rem / 9; // (O,I) parameter index
  float th = theta[pi], f = freq[pi], p = psi[pi], s = sigma[pi];
  float ct = cosf(th), st = sinf(th);
  float rotx = x * ct + y * st;
  float roty = -x * st + y * ct;
  float se = s + 0.001f;
  float g = expf(-0.5f * (rotx * rotx + roty * roty) / (se * se));
  g *= cosf(f * rotx + p);
  g /= (2.0f * 3.14f * s * s);   // reference uses PI = 3.14 exactly
  wp[o * WSTRIDE + rem] = g;
}

// Occupancy-first structure: lane owns 2 consecutive px of ONE output row for
// all 32 o. Window = 3c x 3rows x 4cols = 36 VGPRs -> target <=64 VGPR,
// 8 waves/SIMD (launch_bounds(256,8)). Every store is one fully-dense
// contiguous 512B float2 wave-instr; a block's 4 waves cover one full output
// row (2040B) in-phase. Rows y..y+2 <= 511: no row clamping anywhere.
// XCD chunk swizzle: 8160 blocks, q=1020 -> exactly 2 images per XCD.
__global__ __launch_bounds__(256, 8) void gabor_conv_kernel(
    const float* __restrict__ in, const float* __restrict__ wgp,
    float* __restrict__ out) {
  // Weights per (o,c) padded to 12 floats (float4-aligned rows)
  __shared__ float sW[O_CH][I_CH * 12];

  const int tid = threadIdx.x;
  for (int i = tid; i < O_CH * I_CH * 12; i += 256) {
    int o = i / 36;
    int t = i % 36;
    int c = t / 12;
    int j = t % 12;
    sW[o][t] = (j < 9) ? wgp[o * WSTRIDE + c * 9 + j] : 0.0f;
  }
  __syncthreads();

  const int wave = tid >> 6;   // 0..3 = x-chunk
  const int lane = tid & 63;

  // chunked XCD swizzle (bijective: 8160 % 8 == 0, q = 1020 = 2 images)
  const int bid = blockIdx.x;
  const int q = gridDim.x >> 3;
  const int nid = (bid & 7) * q + (bid >> 3);
  const int n = nid / OH;            // image 0..15
  const int y = nid % OH;            // output row 0..509
  const int x0 = (wave << 7) + (lane << 1);   // 0,2,..,510

  const float* inN = in + (size_t)n * I_CH * IH * IW;
  const int xb = (x0 > IW - 4) ? (IW - 4) : x0;   // clamp only x0=510 lane

  // Input window: 3 ch x 3 rows x 4 cols in 36 VGPRs (rows y..y+2 <= 511)
  float r[I_CH][3][4];
#pragma unroll
  for (int c = 0; c < I_CH; ++c) {
#pragma unroll
    for (int kh = 0; kh < 3; ++kh) {
      const float* rowp = inN + (c * IH + y + kh) * IW + xb;
      v2f A = *(const v2f*)rowp;          // 8B aligned
      v2f B = *(const v2f*)(rowp + 2);
      r[c][kh][0] = A.x; r[c][kh][1] = A.y;
      r[c][kh][2] = B.x; r[c][kh][3] = B.y;
    }
  }

  const bool ok = (x0 <= OW - 2);   // false only for wave 3, lane 63
  float* outN = out + (size_t)n * O_CH * OH * OW + (size_t)y * OW + x0;
  const float4* sW4base = (const float4*)&sW[0][0];

  for (int o = 0; o < O_CH; ++o) {
    float a0 = 0.f, a1 = 0.f;
#pragma unroll
    for (int c = 0; c < I_CH; ++c) {
      const float4* w4 = sW4base + o * 9 + c * 3;   // broadcast ds_read_b128
      float4 w0 = w4[0], w1 = w4[1], w2 = w4[2];
      // kh=0: w0.x w0.y w0.z ; kh=1: w0.w w1.x w1.y ; kh=2: w1.z w1.w w2.x
      a0 = fmaf(r[c][0][0], w0.x, a0); a1 = fmaf(r[c][0][1], w0.x, a1);
      a0 = fmaf(r[c][0][1], w0.y, a0); a1 = fmaf(r[c][0][2], w0.y, a1);
      a0 = fmaf(r[c][0][2], w0.z, a0); a1 = fmaf(r[c][0][3], w0.z, a1);
      a0 = fmaf(r[c][1][0], w0.w, a0); a1 = fmaf(r[c][1][1], w0.w, a1);
      a0 = fmaf(r[c][1][1], w1.x, a0); a1 = fmaf(r[c][1][2], w1.x, a1);
      a0 = fmaf(r[c][1][2], w1.y, a0); a1 = fmaf(r[c][1][3], w1.y, a1);
      a0 = fmaf(r[c][2][0], w1.z, a0); a1 = fmaf(r[c][2][1], w1.z, a1);
      a0 = fmaf(r[c][2][1], w1.w, a0); a1 = fmaf(r[c][2][2], w1.w, a1);
      a0 = fmaf(r[c][2][2], w2.x, a0); a1 = fmaf(r[c][2][3], w2.x, a1);
    }
    if (ok) {
      *(v2f*)(outN + (size_t)o * (OH * OW)) = (v2f){a0, a1};
    }
  }
}

extern "C" void kernel_launch(void* const* d_in, const int* in_sizes, int n_in,
                              void* d_out, int out_size, void* d_ws, size_t ws_size,
                              hipStream_t stream) {
  const float* img   = (const float*)d_in[0];
  const float* freq  = (const float*)d_in[1];
  const float* theta = (const float*)d_in[2];
  const float* psi   = (const float*)d_in[3];
  const float* sigma = (const float*)d_in[4];
  float* outp = (float*)d_out;
  float* wgp = (float*)d_ws;  // 32x32 floats of scratch (Gabor weights)

  gabor_weights_kernel<<<dim3(4), dim3(256), 0, stream>>>(freq, theta, psi, sigma, wgp);

  dim3 grid(N_IMG * OH);   // 8160 blocks; block = one output row (4 x-chunks)
  gabor_conv_kernel<<<grid, dim3(256), 0, stream>>>(img, wgp, outp);
}

// Round 7
// 385.919 us; speedup vs baseline: 2.1399x; 2.1399x over previous
//
#include <hip/hip_runtime.h>
#include <math.h>

#define O_CH 32
#define I_CH 3
#define IH 512
#define IW 512
#define OH 510
#define OW 510
#define N_IMG 16
#define WSTRIDE 32       // weight row stride in d_ws
#define BANDS 128        // 4-row bands per image (last band: 2 valid rows)

typedef float v2f __attribute__((ext_vector_type(2)));
typedef float v4f __attribute__((ext_vector_type(4)));

__global__ __launch_bounds__(256) void gabor_weights_kernel(
    const float* __restrict__ freq, const float* __restrict__ theta,
    const float* __restrict__ psi, const float* __restrict__ sigma,
    float* __restrict__ wp) {
  int idx = blockIdx.x * 256 + threadIdx.x;
  if (idx >= O_CH * I_CH * 9) return;
  int o = idx / 27;
  int rem = idx % 27;          // rem = c*9 + kh*3 + kw
  int kh = (rem / 3) % 3;
  int kw = rem % 3;
  // linspace(-ceil(3/2)+1, ceil(3/2), 3) = {-1, 0.5, 2}
  float x = (kw == 0) ? -1.0f : (kw == 1 ? 0.5f : 2.0f);
  float y = (kh == 0) ? -1.0f : (kh == 1 ? 0.5f : 2.0f);
  int pi = o * I_CH + rem / 9; // (O,I) parameter index
  float th = theta[pi], f = freq[pi], p = psi[pi], s = sigma[pi];
  float ct = cosf(th), st = sinf(th);
  float rotx = x * ct + y * st;
  float roty = -x * st + y * ct;
  float se = s + 0.001f;
  float g = expf(-0.5f * (rotx * rotx + roty * roty) / (se * se));
  g *= cosf(f * rotx + p);
  g /= (2.0f * 3.14f * s * s);   // reference uses PI = 3.14 exactly
  wp[o * WSTRIDE + rem] = g;
}

// Block = ONE o-channel x ONE 4-row band x full width. Wave w owns output row
// band*4+w entirely (lane = 8 consecutive px): every row's 2040B is written
// back-to-back by a single wave -> no intra-row store seams; row-to-row seam
// lines are merged within the block or with the 32-adjacent co-resident
// neighbor block. Window = 3c x 3rows x 10cols = 90 floats + 8 acc -> ~120
// VGPR -> 4 waves/SIMD earned, NOT forced (R5 lesson: launch_bounds(,8)
// squeezed to 32 VGPR, compiler re-fetched the window per o -> 1.77GB FETCH).
// nid order (o fastest, then band) + bijective XCD chunking keeps each band's
// 6 input rows hot in its XCD L2 while 32 o-blocks consume them.
__global__ __launch_bounds__(256) void gabor_conv_kernel(
    const float* __restrict__ in, const float* __restrict__ wgp,
    float* __restrict__ out) {
  __shared__ float sW[I_CH * 12];   // this block's o: 3x9 weights, pad 12

  const int tid = threadIdx.x;

  // bijective chunked XCD swizzle: 65536 blocks, 8192 per XCD
  const int bid = blockIdx.x;
  const int nid = (bid & 7) * (N_IMG * BANDS * O_CH / 8) + (bid >> 3);
  const int o    = nid & 31;
  const int t    = nid >> 5;
  const int band = t & (BANDS - 1);
  const int n    = t >> 7;          // log2(BANDS) = 7

  if (tid < I_CH * 12) {
    int c = tid / 12, j = tid % 12;
    sW[tid] = (j < 9) ? wgp[o * WSTRIDE + c * 9 + j] : 0.0f;
  }
  __syncthreads();

  const int wv = tid >> 6;          // 0..3 -> row within band
  const int lane = tid & 63;
  const int y = band * 4 + wv;      // output row (>=OH possible in last band)
  const int x0 = lane * 8;          // 0,8,...,504

  const float* inN = in + (size_t)n * I_CH * IH * IW;

  // Input window: 3 ch x 3 rows x 10 cols = 90 VGPRs
  float r[I_CH][3][10];
#pragma unroll
  for (int c = 0; c < I_CH; ++c) {
#pragma unroll
    for (int kh = 0; kh < 3; ++kh) {
      int yr = y + kh; if (yr > IH - 1) yr = IH - 1;   // clamps only for masked rows
      const float* rowp = inN + ((size_t)c * IH + yr) * IW;
      v4f A = *(const v4f*)&rowp[x0];        // 16B aligned, cols x0..x0+3
      v4f B = *(const v4f*)&rowp[x0 + 4];    // cols x0+4..x0+7 (<=511)
      int xc = x0 + 8; if (xc > IW - 2) xc = IW - 2;   // lane63 clamp
      v2f C = *(const v2f*)&rowp[xc];
      r[c][kh][0] = A.x; r[c][kh][1] = A.y; r[c][kh][2] = A.z; r[c][kh][3] = A.w;
      r[c][kh][4] = B.x; r[c][kh][5] = B.y; r[c][kh][6] = B.z; r[c][kh][7] = B.w;
      r[c][kh][8] = C.x; r[c][kh][9] = C.y;
    }
  }

  float a[8];
#pragma unroll
  for (int p = 0; p < 8; ++p) a[p] = 0.0f;

#pragma unroll
  for (int c = 0; c < I_CH; ++c) {
    const v4f* w4 = (const v4f*)&sW[c * 12];   // broadcast ds_read_b128 x3
    v4f w0 = w4[0], w1 = w4[1], w2 = w4[2];
    float wq[9];
    wq[0] = w0.x; wq[1] = w0.y; wq[2] = w0.z; wq[3] = w0.w;
    wq[4] = w1.x; wq[5] = w1.y; wq[6] = w1.z; wq[7] = w1.w;
    wq[8] = w2.x;
#pragma unroll
    for (int kh = 0; kh < 3; ++kh) {
#pragma unroll
      for (int kw = 0; kw < 3; ++kw) {
        float w = wq[kh * 3 + kw];
#pragma unroll
        for (int p = 0; p < 8; ++p) {
          a[p] = fmaf(r[c][kh][kw + p], w, a[p]);
        }
      }
    }
  }

  if (y < OH) {
    float* outP = out + ((size_t)n * O_CH + o) * (OH * OW);
    size_t ob = (size_t)y * OW + x0;
    if ((y & 1) == 0) {
      // even row: ob % 4 == 0 -> 16B aligned
      if (x0 + 8 <= OW) {
        *(v4f*)(outP + ob)     = (v4f){a[0], a[1], a[2], a[3]};
        *(v4f*)(outP + ob + 4) = (v4f){a[4], a[5], a[6], a[7]};
      } else {  // lane 63: px 504..509
        *(v4f*)(outP + ob)     = (v4f){a[0], a[1], a[2], a[3]};
        *(v2f*)(outP + ob + 4) = (v2f){a[4], a[5]};
      }
    } else {
      // odd row: ob % 4 == 2 -> 8B aligned float2 pieces
      *(v2f*)(outP + ob)     = (v2f){a[0], a[1]};
      *(v2f*)(outP + ob + 2) = (v2f){a[2], a[3]};
      *(v2f*)(outP + ob + 4) = (v2f){a[4], a[5]};
      if (x0 + 8 <= OW)
        *(v2f*)(outP + ob + 6) = (v2f){a[6], a[7]};
    }
  }
}

extern "C" void kernel_launch(void* const* d_in, const int* in_sizes, int n_in,
                              void* d_out, int out_size, void* d_ws, size_t ws_size,
                              hipStream_t stream) {
  const float* img   = (const float*)d_in[0];
  const float* freq  = (const float*)d_in[1];
  const float* theta = (const float*)d_in[2];
  const float* psi   = (const float*)d_in[3];
  const float* sigma = (const float*)d_in[4];
  float* outp = (float*)d_out;
  float* wgp = (float*)d_ws;  // 32x32 floats of scratch (Gabor weights)

  gabor_weights_kernel<<<dim3(4), dim3(256), 0, stream>>>(freq, theta, psi, sigma, wgp);

  dim3 grid(N_IMG * BANDS * O_CH);   // 65536 blocks: (n, band, o), o fastest
  gabor_conv_kernel<<<grid, dim3(256), 0, stream>>>(img, wgp, outp);
}